// Round 1
// baseline (1659.697 us; speedup 1.0000x reference)
//
#include <hip/hip_runtime.h>
#include <math.h>

#define NN 100000
#define EE 1600000
#define HH 64
#define LL 8
#define NBLK ((NN + 1023) / 1024)

__device__ __forceinline__ float eluf(float x) { return x > 0.0f ? x : expm1f(x); }

// ---------------- CSR build ----------------

__global__ void count_edges_k(const int* __restrict__ dst, int* __restrict__ counts) {
    int i = blockIdx.x * blockDim.x + threadIdx.x;
    if (i < EE) atomicAdd(&counts[dst[i]], 1);
}

__global__ void compute_dinv_k(const int* __restrict__ counts, float* __restrict__ dinv) {
    int i = blockIdx.x * blockDim.x + threadIdx.x;
    if (i < NN) dinv[i] = rsqrtf((float)(counts[i] + 1));  // +1 self loop; deg >= 1 always
}

__global__ void scan_block_k(const int* __restrict__ counts, int* __restrict__ rp,
                             int* __restrict__ partial) {
    __shared__ int sm[256];
    int t = threadIdx.x;
    int base = blockIdx.x * 1024 + t * 4;
    int v0 = 0, v1 = 0, v2 = 0, v3 = 0;
    if (base + 0 < NN) v0 = counts[base + 0];
    if (base + 1 < NN) v1 = counts[base + 1];
    if (base + 2 < NN) v2 = counts[base + 2];
    if (base + 3 < NN) v3 = counts[base + 3];
    int s = v0 + v1 + v2 + v3;
    sm[t] = s;
    __syncthreads();
    for (int off = 1; off < 256; off <<= 1) {
        int x = 0;
        if (t >= off) x = sm[t - off];
        __syncthreads();
        if (t >= off) sm[t] += x;
        __syncthreads();
    }
    int excl = sm[t] - s;
    if (t == 255) partial[blockIdx.x] = sm[255];
    if (base + 0 < NN) rp[base + 0] = excl;
    excl += v0;
    if (base + 1 < NN) rp[base + 1] = excl;
    excl += v1;
    if (base + 2 < NN) rp[base + 2] = excl;
    excl += v2;
    if (base + 3 < NN) rp[base + 3] = excl;
}

__global__ void scan_top_k(int* partial) {
    __shared__ int sm[128];
    int t = threadIdx.x;
    int v = (t < NBLK) ? partial[t] : 0;
    sm[t] = v;
    __syncthreads();
    for (int off = 1; off < 128; off <<= 1) {
        int x = 0;
        if (t >= off) x = sm[t - off];
        __syncthreads();
        if (t >= off) sm[t] += x;
        __syncthreads();
    }
    if (t < NBLK) partial[t] = sm[t] - v;  // exclusive
}

__global__ void scan_add_k(int* rp, const int* __restrict__ partial) {
    int i = blockIdx.x * blockDim.x + threadIdx.x;
    if (i < NN) rp[i] += partial[i >> 10];
    else if (i == NN) rp[NN] = EE;
}

__global__ void scatter_k(const int* __restrict__ src, const int* __restrict__ dst,
                          const int* __restrict__ rp, int* __restrict__ fill,
                          const float* __restrict__ dinv, int* __restrict__ col,
                          float* __restrict__ val) {
    int e = blockIdx.x * blockDim.x + threadIdx.x;
    if (e < EE) {
        int d = dst[e], s = src[e];
        int pos = rp[d] + atomicAdd(&fill[d], 1);
        col[pos] = s;
        val[pos] = dinv[s] * dinv[d];
    }
}

// ---------------- SpMM: s = 0.5*(P_hat @ h) + 0.5*x0 ----------------
// One wave per node: 64 lanes = 64 features. Edge cols/vals are lane-batched
// then broadcast via shfl; h[src] gather is 256B contiguous per edge.

__global__ __launch_bounds__(256) void spmm_k(
    const int* __restrict__ rp, const int* __restrict__ col, const float* __restrict__ val,
    const float* __restrict__ dinv, const float* __restrict__ h, const float* __restrict__ x0,
    float* __restrict__ sout) {
    int node = blockIdx.x * 4 + (threadIdx.x >> 6);
    int lane = threadIdx.x & 63;
    if (node >= NN) return;
    int start = rp[node], end = rp[node + 1];
    float acc = 0.0f;
    for (int e = start; e < end; e += 64) {
        int me = e + lane;
        int c = 0;
        float v = 0.0f;
        if (me < end) { c = col[me]; v = val[me]; }
        int cnt = min(64, end - e);
        for (int j = 0; j < cnt; ++j) {
            int cj = __shfl(c, j, 64);
            float vj = __shfl(v, j, 64);
            acc = fmaf(vj, h[(size_t)cj * HH + lane], acc);
        }
    }
    float di = dinv[node];
    acc = fmaf(di * di, h[(size_t)node * HH + lane], acc);  // self loop
    sout[(size_t)node * HH + lane] = 0.5f * acc + 0.5f * x0[(size_t)node * HH + lane];
}

// ---------------- GEMM: out[N,64] = A[N,KTOT] @ B[KTOT,64] (+epilogue) ----------------
// MODE 0: input layer  -> out = elu(A@B + bias)
// MODE 1: GCNII layer  -> B' = beta*B + (1-beta)*I loaded into LDS; out = elu(o)+o
// MODE 2: output layer -> out = A@B + bias
// 256 threads/block -> 64x64 output tile, 4x4 register tile per thread.

template <int KTOT, int MODE>
__global__ __launch_bounds__(256) void gemm_k(const float* __restrict__ A,
                                              const float* __restrict__ B,
                                              const float* __restrict__ bias, float beta,
                                              float* __restrict__ out) {
    __shared__ float ss[64][68];  // 272B row stride: 16B-aligned, conflict-friendly
    __shared__ float ws[64][64];
    int t = threadIdx.x;
    int row0 = blockIdx.x * 64;
    int tx = t & 15, ty = t >> 4;
    float acc[4][4] = {};

    for (int kc = 0; kc < KTOT; kc += 64) {
#pragma unroll
        for (int i = 0; i < 4; ++i) {
            int linear = t + i * 256;
            int r = linear >> 4, q = linear & 15;
            int grow = row0 + r;
            float4 v = make_float4(0.f, 0.f, 0.f, 0.f);
            if (grow < NN) v = *(const float4*)&A[(size_t)grow * KTOT + kc + q * 4];
            *(float4*)&ss[r][q * 4] = v;
        }
#pragma unroll
        for (int i = 0; i < 4; ++i) {
            int linear = t + i * 256;
            int r = linear >> 4, q = linear & 15;
            float4 v = *(const float4*)&B[(size_t)(kc + r) * 64 + q * 4];
            if (MODE == 1) {
                v.x *= beta; v.y *= beta; v.z *= beta; v.w *= beta;
                int diff = r - q * 4;
                if (diff == 0) v.x += 1.0f - beta;
                else if (diff == 1) v.y += 1.0f - beta;
                else if (diff == 2) v.z += 1.0f - beta;
                else if (diff == 3) v.w += 1.0f - beta;
            }
            *(float4*)&ws[r][q * 4] = v;
        }
        __syncthreads();
#pragma unroll
        for (int k = 0; k < 64; k += 4) {
            float4 af[4], bf[4];
            af[0] = *(const float4*)&ss[ty * 4 + 0][k];
            af[1] = *(const float4*)&ss[ty * 4 + 1][k];
            af[2] = *(const float4*)&ss[ty * 4 + 2][k];
            af[3] = *(const float4*)&ss[ty * 4 + 3][k];
            bf[0] = *(const float4*)&ws[k + 0][tx * 4];
            bf[1] = *(const float4*)&ws[k + 1][tx * 4];
            bf[2] = *(const float4*)&ws[k + 2][tx * 4];
            bf[3] = *(const float4*)&ws[k + 3][tx * 4];
            const float* A4 = (const float*)af;  // A4[i*4+kk]
            const float* B4 = (const float*)bf;  // B4[kk*4+j]
#pragma unroll
            for (int i = 0; i < 4; ++i)
#pragma unroll
                for (int kk = 0; kk < 4; ++kk)
#pragma unroll
                    for (int j = 0; j < 4; ++j)
                        acc[i][j] = fmaf(A4[i * 4 + kk], B4[kk * 4 + j], acc[i][j]);
        }
        __syncthreads();
    }

#pragma unroll
    for (int i = 0; i < 4; ++i) {
        int r = row0 + ty * 4 + i;
        if (r >= NN) continue;
        float4 o;
        float* op = (float*)&o;
#pragma unroll
        for (int j = 0; j < 4; ++j) {
            float xv = acc[i][j];
            if (MODE == 0) { xv += bias[tx * 4 + j]; xv = eluf(xv); }
            else if (MODE == 1) { xv = eluf(xv) + xv; }
            else { xv += bias[tx * 4 + j]; }
            op[j] = xv;
        }
        *(float4*)&out[(size_t)r * 64 + tx * 4] = o;
    }
}

// ---------------- launch ----------------

extern "C" void kernel_launch(void* const* d_in, const int* in_sizes, int n_in, void* d_out,
                              int out_size, void* d_ws, size_t ws_size, hipStream_t stream) {
    const float* x = (const float*)d_in[0];
    const int* ei = (const int*)d_in[1];  // [2][E] int32
    const float* w_in = (const float*)d_in[2];
    const float* b_in = (const float*)d_in[3];
    const float* w_layers = (const float*)d_in[4];
    const float* w_out = (const float*)d_in[5];
    const float* b_out = (const float*)d_in[6];
    float* out = (float*)d_out;

    char* p = (char*)d_ws;
    auto alloc = [&](size_t bytes) -> char* {
        char* r = p;
        p += (bytes + 255) & ~(size_t)255;
        return r;
    };
    int* counts = (int*)alloc((size_t)NN * 4);
    int* fill = (int*)alloc((size_t)NN * 4);
    int* rp = (int*)alloc((size_t)(NN + 1) * 4);
    int* partial = (int*)alloc(128 * 4);
    float* dinv = (float*)alloc((size_t)NN * 4);
    int* colA = (int*)alloc((size_t)EE * 4);
    float* valA = (float*)alloc((size_t)EE * 4);
    float* x0 = (float*)alloc((size_t)NN * HH * 4);
    float* hbuf = (float*)alloc((size_t)NN * HH * 4);
    float* sbuf = (float*)alloc((size_t)NN * HH * 4);

    const int* srcA = ei;
    const int* dstA = ei + EE;

    hipMemsetAsync(counts, 0, (size_t)NN * 4, stream);
    hipMemsetAsync(fill, 0, (size_t)NN * 4, stream);
    count_edges_k<<<(EE + 255) / 256, 256, 0, stream>>>(dstA, counts);
    compute_dinv_k<<<(NN + 255) / 256, 256, 0, stream>>>(counts, dinv);
    scan_block_k<<<NBLK, 256, 0, stream>>>(counts, rp, partial);
    scan_top_k<<<1, 128, 0, stream>>>(partial);
    scan_add_k<<<(NN + 1 + 255) / 256, 256, 0, stream>>>(rp, partial);
    scatter_k<<<(EE + 255) / 256, 256, 0, stream>>>(srcA, dstA, rp, fill, dinv, colA, valA);

    // h0 = x0 = elu(x @ w_in + b_in)
    gemm_k<256, 0><<<(NN + 63) / 64, 256, 0, stream>>>(x, w_in, b_in, 0.0f, x0);

    for (int l = 0; l < LL; ++l) {
        float beta = (float)log(1.0 / (double)(l + 1) + 1.0);
        const float* hin = (l == 0) ? x0 : hbuf;
        spmm_k<<<(NN + 3) / 4, 256, 0, stream>>>(rp, colA, valA, dinv, hin, x0, sbuf);
        gemm_k<64, 1><<<(NN + 63) / 64, 256, 0, stream>>>(sbuf, w_layers + (size_t)l * 64 * 64,
                                                          nullptr, beta, hbuf);
    }
    gemm_k<64, 2><<<(NN + 63) / 64, 256, 0, stream>>>(hbuf, w_out, b_out, 0.0f, out);
}

// Round 2
// 1200.155 us; speedup vs baseline: 1.3829x; 1.3829x over previous
//
#include <hip/hip_runtime.h>
#include <hip/hip_fp16.h>
#include <math.h>

#define NN 100000
#define EE 1600000
#define HH 64
#define LL 8
#define NBLK ((NN + 1023) / 1024)

__device__ __forceinline__ float eluf(float x) { return x > 0.0f ? x : expm1f(x); }

// ---------------- CSR build ----------------

__global__ void count_edges_k(const int* __restrict__ dst, int* __restrict__ counts) {
    int i = blockIdx.x * blockDim.x + threadIdx.x;
    if (i < EE) atomicAdd(&counts[dst[i]], 1);
}

__global__ void scan_block_k(const int* __restrict__ counts, int* __restrict__ rp,
                             int* __restrict__ partial, float* __restrict__ dinv) {
    __shared__ int sm[256];
    int t = threadIdx.x;
    int base = blockIdx.x * 1024 + t * 4;
    int v0 = 0, v1 = 0, v2 = 0, v3 = 0;
    if (base + 0 < NN) v0 = counts[base + 0];
    if (base + 1 < NN) v1 = counts[base + 1];
    if (base + 2 < NN) v2 = counts[base + 2];
    if (base + 3 < NN) v3 = counts[base + 3];
    // fused: dinv = rsqrt(deg + self loop)
    if (base + 0 < NN) dinv[base + 0] = rsqrtf((float)(v0 + 1));
    if (base + 1 < NN) dinv[base + 1] = rsqrtf((float)(v1 + 1));
    if (base + 2 < NN) dinv[base + 2] = rsqrtf((float)(v2 + 1));
    if (base + 3 < NN) dinv[base + 3] = rsqrtf((float)(v3 + 1));
    int s = v0 + v1 + v2 + v3;
    sm[t] = s;
    __syncthreads();
    for (int off = 1; off < 256; off <<= 1) {
        int x = 0;
        if (t >= off) x = sm[t - off];
        __syncthreads();
        if (t >= off) sm[t] += x;
        __syncthreads();
    }
    int excl = sm[t] - s;
    if (t == 255) partial[blockIdx.x] = sm[255];
    if (base + 0 < NN) rp[base + 0] = excl;
    excl += v0;
    if (base + 1 < NN) rp[base + 1] = excl;
    excl += v1;
    if (base + 2 < NN) rp[base + 2] = excl;
    excl += v2;
    if (base + 3 < NN) rp[base + 3] = excl;
}

__global__ void scan_top_k(int* partial) {
    __shared__ int sm[128];
    int t = threadIdx.x;
    int v = (t < NBLK) ? partial[t] : 0;
    sm[t] = v;
    __syncthreads();
    for (int off = 1; off < 128; off <<= 1) {
        int x = 0;
        if (t >= off) x = sm[t - off];
        __syncthreads();
        if (t >= off) sm[t] += x;
        __syncthreads();
    }
    if (t < NBLK) partial[t] = sm[t] - v;  // exclusive
}

__global__ void scan_add_k(int* rp, const int* __restrict__ partial) {
    int i = blockIdx.x * blockDim.x + threadIdx.x;
    if (i < NN) rp[i] += partial[i >> 10];
    else if (i == NN) rp[NN] = EE;
}

// Edge payload: {col, val} interleaved -> ONE 8B random write per edge
// (halves write-allocate line traffic vs two 4B writes to separate arrays).
__global__ void scatter_k(const int* __restrict__ src, const int* __restrict__ dst,
                          const int* __restrict__ rp, int* __restrict__ fill,
                          const float* __restrict__ dinv, int2* __restrict__ edge) {
    int e = blockIdx.x * blockDim.x + threadIdx.x;
    if (e < EE) {
        int d = dst[e], s = src[e];
        int pos = rp[d] + atomicAdd(&fill[d], 1);
        int2 ev;
        ev.x = s;
        ev.y = __float_as_int(dinv[s] * dinv[d]);
        edge[pos] = ev;
    }
}

// ---------------- SpMM: s = 0.5*(P_hat @ h) + 0.5*x0 ----------------
// One wave per node: 64 lanes = 64 features. Gather operand h is fp16
// (halves gather bytes: 128B/edge). Invalid lanes zero-padded so the inner
// loop unrolls by 4 without per-j bounds checks (4 independent loads -> ILP).

__global__ __launch_bounds__(256) void spmm_k(
    const int* __restrict__ rp, const int2* __restrict__ edge, const float* __restrict__ dinv,
    const __half* __restrict__ h16, const float* __restrict__ x0, float* __restrict__ sout) {
    int node = blockIdx.x * 4 + (threadIdx.x >> 6);
    int lane = threadIdx.x & 63;
    if (node >= NN) return;
    int start = rp[node], end = rp[node + 1];
    float acc = 0.0f;
    for (int e = start; e < end; e += 64) {
        int me = e + lane;
        int c = 0;
        float v = 0.0f;
        if (me < end) {
            int2 ev = edge[me];
            c = ev.x;
            v = __int_as_float(ev.y);
        }
        int cnt4 = (min(64, end - e) + 3) & ~3;
        for (int j = 0; j < cnt4; j += 4) {
#pragma unroll
            for (int u = 0; u < 4; ++u) {
                int cj = __shfl(c, j + u, 64);
                float vj = __shfl(v, j + u, 64);
                acc = fmaf(vj, __half2float(h16[(size_t)cj * HH + lane]), acc);
            }
        }
    }
    float di = dinv[node];
    acc = fmaf(di * di, __half2float(h16[(size_t)node * HH + lane]), acc);  // self loop
    sout[(size_t)node * HH + lane] = 0.5f * acc + 0.5f * x0[(size_t)node * HH + lane];
}

// ---------------- GEMM: out[N,64] = A[N,KTOT] @ B[KTOT,64] (+epilogue) ----------------
// MODE 0: input layer  -> out32 = elu(A@B + bias); also writes out16 (gather copy)
// MODE 1: GCNII layer  -> B' = beta*B + (1-beta)*I; o=A@B'; h=elu(o)+o -> out16;
//                         optionally out32 (in-place into A is safe: KTOT=64 is a
//                         single LDS chunk, block stages its A rows before writing)
// MODE 2: output layer -> out32 = A@B + bias  (A is fp32)
// 256 threads/block -> 64x64 output tile, 4x4 register tile per thread.

template <int KTOT, int MODE>
__global__ __launch_bounds__(256) void gemm_k(const float* __restrict__ A,
                                              const float* __restrict__ B,
                                              const float* __restrict__ bias, float beta,
                                              float* __restrict__ out32,
                                              __half* __restrict__ out16, int write32) {
    __shared__ float ss[64][68];  // 272B row stride: 16B-aligned, conflict-friendly
    __shared__ float ws[64][64];
    int t = threadIdx.x;
    int row0 = blockIdx.x * 64;
    int tx = t & 15, ty = t >> 4;
    float acc[4][4] = {};

    for (int kc = 0; kc < KTOT; kc += 64) {
#pragma unroll
        for (int i = 0; i < 4; ++i) {
            int linear = t + i * 256;
            int r = linear >> 4, q = linear & 15;
            int grow = row0 + r;
            float4 v = make_float4(0.f, 0.f, 0.f, 0.f);
            if (grow < NN) v = *(const float4*)&A[(size_t)grow * KTOT + kc + q * 4];
            *(float4*)&ss[r][q * 4] = v;
        }
#pragma unroll
        for (int i = 0; i < 4; ++i) {
            int linear = t + i * 256;
            int r = linear >> 4, q = linear & 15;
            float4 v = *(const float4*)&B[(size_t)(kc + r) * 64 + q * 4];
            if (MODE == 1) {
                v.x *= beta; v.y *= beta; v.z *= beta; v.w *= beta;
                int diff = r - q * 4;
                if (diff == 0) v.x += 1.0f - beta;
                else if (diff == 1) v.y += 1.0f - beta;
                else if (diff == 2) v.z += 1.0f - beta;
                else if (diff == 3) v.w += 1.0f - beta;
            }
            *(float4*)&ws[r][q * 4] = v;
        }
        __syncthreads();
#pragma unroll
        for (int k = 0; k < 64; k += 4) {
            float4 af[4], bf[4];
            af[0] = *(const float4*)&ss[ty * 4 + 0][k];
            af[1] = *(const float4*)&ss[ty * 4 + 1][k];
            af[2] = *(const float4*)&ss[ty * 4 + 2][k];
            af[3] = *(const float4*)&ss[ty * 4 + 3][k];
            bf[0] = *(const float4*)&ws[k + 0][tx * 4];
            bf[1] = *(const float4*)&ws[k + 1][tx * 4];
            bf[2] = *(const float4*)&ws[k + 2][tx * 4];
            bf[3] = *(const float4*)&ws[k + 3][tx * 4];
            const float* A4 = (const float*)af;  // A4[i*4+kk]
            const float* B4 = (const float*)bf;  // B4[kk*4+j]
#pragma unroll
            for (int i = 0; i < 4; ++i)
#pragma unroll
                for (int kk = 0; kk < 4; ++kk)
#pragma unroll
                    for (int j = 0; j < 4; ++j)
                        acc[i][j] = fmaf(A4[i * 4 + kk], B4[kk * 4 + j], acc[i][j]);
        }
        __syncthreads();
    }

#pragma unroll
    for (int i = 0; i < 4; ++i) {
        int r = row0 + ty * 4 + i;
        if (r >= NN) continue;
        float4 o;
        float* op = (float*)&o;
#pragma unroll
        for (int j = 0; j < 4; ++j) {
            float xv = acc[i][j];
            if (MODE == 0) { xv += bias[tx * 4 + j]; xv = eluf(xv); }
            else if (MODE == 1) { xv = eluf(xv) + xv; }
            else { xv += bias[tx * 4 + j]; }
            op[j] = xv;
        }
        if (MODE == 2 || write32) *(float4*)&out32[(size_t)r * 64 + tx * 4] = o;
        if (MODE != 2) {
            __half2* hp = (__half2*)&out16[(size_t)r * 64 + tx * 4];
            hp[0] = __floats2half2_rn(o.x, o.y);
            hp[1] = __floats2half2_rn(o.z, o.w);
        }
    }
}

// ---------------- launch ----------------

extern "C" void kernel_launch(void* const* d_in, const int* in_sizes, int n_in, void* d_out,
                              int out_size, void* d_ws, size_t ws_size, hipStream_t stream) {
    const float* x = (const float*)d_in[0];
    const int* ei = (const int*)d_in[1];  // [2][E] int32
    const float* w_in = (const float*)d_in[2];
    const float* b_in = (const float*)d_in[3];
    const float* w_layers = (const float*)d_in[4];
    const float* w_out = (const float*)d_in[5];
    const float* b_out = (const float*)d_in[6];
    float* out = (float*)d_out;

    char* p = (char*)d_ws;
    auto alloc = [&](size_t bytes) -> char* {
        char* r = p;
        p += (bytes + 255) & ~(size_t)255;
        return r;
    };
    int* counts = (int*)alloc((size_t)NN * 4);
    int* fill = (int*)alloc((size_t)NN * 4);
    int* rp = (int*)alloc((size_t)(NN + 1) * 4);
    int* partial = (int*)alloc(128 * 4);
    float* dinv = (float*)alloc((size_t)NN * 4);
    int2* edge = (int2*)alloc((size_t)EE * 8);
    float* x0 = (float*)alloc((size_t)NN * HH * 4);         // fp32 residual
    __half* x0h = (__half*)alloc((size_t)NN * HH * 2);      // fp16 gather copy (layer 0)
    __half* hbuf16 = (__half*)alloc((size_t)NN * HH * 2);   // fp16 gather copy (layers 1..)
    float* sbuf = (float*)alloc((size_t)NN * HH * 4);       // fp32 s / final fp32 h

    const int* srcA = ei;
    const int* dstA = ei + EE;

    hipMemsetAsync(counts, 0, (size_t)NN * 4, stream);
    hipMemsetAsync(fill, 0, (size_t)NN * 4, stream);
    count_edges_k<<<(EE + 255) / 256, 256, 0, stream>>>(dstA, counts);
    scan_block_k<<<NBLK, 256, 0, stream>>>(counts, rp, partial, dinv);
    scan_top_k<<<1, 128, 0, stream>>>(partial);
    scan_add_k<<<(NN + 1 + 255) / 256, 256, 0, stream>>>(rp, partial);
    scatter_k<<<(EE + 255) / 256, 256, 0, stream>>>(srcA, dstA, rp, fill, dinv, edge);

    // h0 = x0 = elu(x @ w_in + b_in)  (fp32 + fp16 copies)
    gemm_k<256, 0><<<(NN + 63) / 64, 256, 0, stream>>>(x, w_in, b_in, 0.0f, x0, x0h, 1);

    for (int l = 0; l < LL; ++l) {
        float beta = (float)log(1.0 / (double)(l + 1) + 1.0);
        const __half* hin = (l == 0) ? x0h : hbuf16;
        spmm_k<<<(NN + 3) / 4, 256, 0, stream>>>(rp, edge, dinv, hin, x0, sbuf);
        // l=7: also write fp32 h in-place into sbuf for the (precision-sensitive) output GEMM
        gemm_k<64, 1><<<(NN + 63) / 64, 256, 0, stream>>>(
            sbuf, w_layers + (size_t)l * 64 * 64, nullptr, beta, sbuf, hbuf16, l == LL - 1);
    }
    gemm_k<64, 2><<<(NN + 63) / 64, 256, 0, stream>>>(sbuf, w_out, b_out, 0.0f, out, nullptr, 1);
}